// Round 1
// baseline (3383.078 us; speedup 1.0000x reference)
//
#include <hip/hip_runtime.h>
#include <math.h>

#define NN 50000
#define NE 800000
#define IND 256
#define NH 64
#define DEPTH 4

// ---------------- CSR build ----------------

__global__ void count_deg(const int* __restrict__ src, const int* __restrict__ dst,
                          int* __restrict__ degin, int* __restrict__ degout) {
    int e = blockIdx.x * blockDim.x + threadIdx.x;
    if (e < NE) {
        atomicAdd(&degout[src[e]], 1);
        atomicAdd(&degin[dst[e]], 1);
    }
}

// single-block exclusive scan of n ints, out has n+1 entries (out[n] = total)
__global__ void scan_excl(const int* __restrict__ in, int* __restrict__ out, int n) {
    __shared__ int sums[1024];
    int t = threadIdx.x;
    int chunk = (n + 1023) / 1024;
    int lo = t * chunk;
    int hi = lo + chunk; if (hi > n) hi = n;
    int s = 0;
    for (int i = lo; i < hi; ++i) s += in[i];
    sums[t] = s;
    __syncthreads();
    for (int off = 1; off < 1024; off <<= 1) {
        int v = (t >= off) ? sums[t - off] : 0;
        __syncthreads();
        sums[t] += v;
        __syncthreads();
    }
    int run = (t == 0) ? 0 : sums[t - 1];
    for (int i = lo; i < hi; ++i) { out[i] = run; run += in[i]; }
    if (t == 0) out[n] = sums[1023];
}

__global__ void init_node(const int* __restrict__ degin, const int* __restrict__ degout,
                          const int* __restrict__ off_dst, const int* __restrict__ off_src,
                          int* __restrict__ cur_dst, int* __restrict__ cur_src,
                          float* __restrict__ dis, float* __restrict__ cntf) {
    int i = blockIdx.x * blockDim.x + threadIdx.x;
    if (i < NN) {
        dis[i] = rsqrtf((float)(degin[i] + 1));   // +1 self loop; always >0
        int od = degout[i];
        cntf[i] = (float)(od > 0 ? od : 1);
        cur_dst[i] = off_dst[i];
        cur_src[i] = off_src[i];
    }
}

__global__ void fill_csr(const int* __restrict__ src, const int* __restrict__ dst,
                         int* __restrict__ cur_dst, int* __restrict__ cur_src,
                         int* __restrict__ srcs_by_dst, int* __restrict__ dsts_by_src) {
    int e = blockIdx.x * blockDim.x + threadIdx.x;
    if (e < NE) {
        int s = src[e], d = dst[e];
        int p = atomicAdd(&cur_dst[d], 1);
        srcs_by_dst[p] = s;
        int q = atomicAdd(&cur_src[s], 1);
        dsts_by_src[q] = d;
    }
}

// ---------------- GEMM: [n,K] @ [K,64] ----------------
// SCALE: out = rowscale[row] * (X@W)         (no bias, no relu)  -- conv path
// else : out = relu(X@W + bias)                                  -- enc/dec path
template<int K, bool RELU, bool SCALE>
__global__ void gemm64(const float* __restrict__ X, const float* __restrict__ W,
                       const float* __restrict__ bias, const float* __restrict__ rowscale,
                       float* __restrict__ out, int n) {
    __shared__ float Ws[64 * 64];
    __shared__ float Xs[16][68];      // +4 pad: row_l stride 68 -> 4 distinct banks
    int tid = threadIdx.x;
    int row0 = blockIdx.x * 16;
    int row_l = tid >> 4;             // 0..15
    int cg = tid & 15;                // 0..15 (4 cols each)
    float4 acc = {0.f, 0.f, 0.f, 0.f};

    for (int kc = 0; kc < K; kc += 64) {
        const float4* W4 = (const float4*)(W + (size_t)kc * 64);
        float4* Ws4 = (float4*)Ws;
#pragma unroll
        for (int t = 0; t < 4; ++t) Ws4[tid + t * 256] = W4[tid + t * 256];
        {
            int r = tid >> 4, c4 = tid & 15;
            int grow = row0 + r;
            float4 xv = {0.f, 0.f, 0.f, 0.f};
            if (grow < n) xv = *(const float4*)(X + (size_t)grow * K + kc + c4 * 4);
            Xs[r][c4 * 4 + 0] = xv.x;
            Xs[r][c4 * 4 + 1] = xv.y;
            Xs[r][c4 * 4 + 2] = xv.z;
            Xs[r][c4 * 4 + 3] = xv.w;
        }
        __syncthreads();
#pragma unroll
        for (int k = 0; k < 64; ++k) {
            float xv = Xs[row_l][k];
            float4 w4 = ((const float4*)Ws)[k * 16 + cg];
            acc.x += xv * w4.x; acc.y += xv * w4.y;
            acc.z += xv * w4.z; acc.w += xv * w4.w;
        }
        __syncthreads();
    }

    int row = row0 + row_l;
    if (row < n) {
        if (SCALE) {
            float s = rowscale[row];
            acc.x *= s; acc.y *= s; acc.z *= s; acc.w *= s;
        } else {
            float4 b4 = ((const float4*)bias)[cg];
            acc.x += b4.x; acc.y += b4.y; acc.z += b4.z; acc.w += b4.w;
        }
        if (RELU) {
            acc.x = fmaxf(acc.x, 0.f); acc.y = fmaxf(acc.y, 0.f);
            acc.z = fmaxf(acc.z, 0.f); acc.w = fmaxf(acc.w, 0.f);
        }
        ((float4*)(out + (size_t)row * 64))[cg] = acc;
    }
}

// ---------------- aggregation: one wave per node, lane = channel ----------------
// A holds dis[i]*xw[i]. out[i] = relu(dis[i]*(A[i] + sum_{s in in(i)} A[s]) + b)
__global__ void agg_conv(const float* __restrict__ A, const int* __restrict__ off,
                         const int* __restrict__ nbr, const float* __restrict__ dis,
                         const float* __restrict__ bias, float* __restrict__ out) {
    int node = blockIdx.x * 4 + (threadIdx.x >> 6);
    int lane = threadIdx.x & 63;
    if (node >= NN) return;
    size_t base = (size_t)node * 64 + lane;
    float acc = A[base];
    int lo = off[node], hi = off[node + 1];
    for (int j = lo; j < hi; ++j) {
        int s = nbr[j];
        acc += A[(size_t)s * 64 + lane];
    }
    float v = dis[node] * acc + bias[lane];
    out[base] = fmaxf(v, 0.f);
}

// ---------------- gate + convex update ----------------
// tau = tanh( sum_{d in out(i)} (xg_i - xg_d)^2 / max(outdeg,1) )
// X = (1-tau)*X + tau*Xnew
__global__ void gate_update(const float* __restrict__ XG, const float* __restrict__ Xn,
                            float* __restrict__ X, const int* __restrict__ off,
                            const int* __restrict__ nbr, const float* __restrict__ cntf) {
    int node = blockIdx.x * 4 + (threadIdx.x >> 6);
    int lane = threadIdx.x & 63;
    if (node >= NN) return;
    size_t base = (size_t)node * 64 + lane;
    float xg = XG[base];
    float acc = 0.f;
    int lo = off[node], hi = off[node + 1];
    for (int j = lo; j < hi; ++j) {
        int d = nbr[j];
        float diff = xg - XG[(size_t)d * 64 + lane];
        acc += diff * diff;
    }
    float tau = tanhf(acc / cntf[node]);
    X[base] = (1.f - tau) * X[base] + tau * Xn[base];
}

// ---------------- launch ----------------

extern "C" void kernel_launch(void* const* d_in, const int* in_sizes, int n_in,
                              void* d_out, int out_size, void* d_ws, size_t ws_size,
                              hipStream_t stream) {
    const float* x      = (const float*)d_in[0];
    const int*   ei     = (const int*)d_in[1];
    const float* enc_w  = (const float*)d_in[2];
    const float* enc_b  = (const float*)d_in[3];
    const float* conv_w = (const float*)d_in[4];
    const float* conv_b = (const float*)d_in[5];
    const float* gg_w   = (const float*)d_in[6];
    const float* gg_b   = (const float*)d_in[7];
    const float* dec_w  = (const float*)d_in[8];
    const float* dec_b  = (const float*)d_in[9];
    float* out = (float*)d_out;

    const int* src = ei;
    const int* dst = ei + NE;

    char* p = (char*)d_ws;
    auto alloc = [&](size_t bytes) -> void* {
        void* r = (void*)p;
        p += (bytes + 255) & ~(size_t)255;
        return r;
    };
    float* X    = (float*)alloc((size_t)NN * 64 * 4);
    float* A    = (float*)alloc((size_t)NN * 64 * 4);
    float* B    = (float*)alloc((size_t)NN * 64 * 4);   // X_ candidate
    float* C    = (float*)alloc((size_t)NN * 64 * 4);   // xg
    float* dis  = (float*)alloc((size_t)NN * 4);
    float* cntf = (float*)alloc((size_t)NN * 4);
    int* degin   = (int*)alloc((size_t)NN * 4);
    int* degout  = (int*)alloc((size_t)NN * 4);
    int* off_dst = (int*)alloc((size_t)(NN + 1) * 4);
    int* off_src = (int*)alloc((size_t)(NN + 1) * 4);
    int* cur_dst = (int*)alloc((size_t)NN * 4);
    int* cur_src = (int*)alloc((size_t)NN * 4);
    int* sbd     = (int*)alloc((size_t)NE * 4);   // srcs grouped by dst
    int* dbs     = (int*)alloc((size_t)NE * 4);   // dsts grouped by src

    hipMemsetAsync(degin, 0, (size_t)NN * 4, stream);
    hipMemsetAsync(degout, 0, (size_t)NN * 4, stream);

    const int EB = (NE + 255) / 256;
    const int NB = (NN + 255) / 256;
    count_deg<<<EB, 256, 0, stream>>>(src, dst, degin, degout);
    scan_excl<<<1, 1024, 0, stream>>>(degin, off_dst, NN);
    scan_excl<<<1, 1024, 0, stream>>>(degout, off_src, NN);
    init_node<<<NB, 256, 0, stream>>>(degin, degout, off_dst, off_src,
                                      cur_dst, cur_src, dis, cntf);
    fill_csr<<<EB, 256, 0, stream>>>(src, dst, cur_dst, cur_src, sbd, dbs);

    const int GB = (NN + 15) / 16;   // gemm blocks
    const int AB = (NN + 3) / 4;     // per-node-wave blocks

    // encoder
    gemm64<IND, true, false><<<GB, 256, 0, stream>>>(x, enc_w, enc_b, nullptr, X, NN);

    for (int l = 0; l < DEPTH; ++l) {
        // conv path: A = dis .* (X @ conv_w); B = relu(dis*(A_self+sum)+b)
        gemm64<NH, false, true><<<GB, 256, 0, stream>>>(X, conv_w, nullptr, dis, A, NN);
        agg_conv<<<AB, 256, 0, stream>>>(A, off_dst, sbd, dis, conv_b, B);
        // gate conv: C = xg
        gemm64<NH, false, true><<<GB, 256, 0, stream>>>(X, gg_w, nullptr, dis, A, NN);
        agg_conv<<<AB, 256, 0, stream>>>(A, off_dst, sbd, dis, gg_b, C);
        // tau + update
        gate_update<<<AB, 256, 0, stream>>>(C, B, X, off_src, dbs, cntf);
    }

    // decoder
    gemm64<NH, true, false><<<GB, 256, 0, stream>>>(X, dec_w, dec_b, nullptr, out, NN);
}

// Round 2
// 1203.351 us; speedup vs baseline: 2.8114x; 2.8114x over previous
//
#include <hip/hip_runtime.h>
#include <math.h>

#define NN 50000
#define NE 800000
#define IND 256
#define NH 64
#define DEPTH 4
#define NPW 8   // nodes per wave in gather kernels

// ---------------- CSR build ----------------

__global__ void count_deg(const int* __restrict__ src, const int* __restrict__ dst,
                          int* __restrict__ degin, int* __restrict__ degout) {
    int e = blockIdx.x * blockDim.x + threadIdx.x;
    if (e < NE) {
        atomicAdd(&degout[src[e]], 1);
        atomicAdd(&degin[dst[e]], 1);
    }
}

// single-block exclusive scan of n ints, out has n+1 entries (out[n] = total)
__global__ void scan_excl(const int* __restrict__ in, int* __restrict__ out, int n) {
    __shared__ int sums[1024];
    int t = threadIdx.x;
    int chunk = (n + 1023) / 1024;
    int lo = t * chunk;
    int hi = lo + chunk; if (hi > n) hi = n;
    int s = 0;
    for (int i = lo; i < hi; ++i) s += in[i];
    sums[t] = s;
    __syncthreads();
    for (int off = 1; off < 1024; off <<= 1) {
        int v = (t >= off) ? sums[t - off] : 0;
        __syncthreads();
        sums[t] += v;
        __syncthreads();
    }
    int run = (t == 0) ? 0 : sums[t - 1];
    for (int i = lo; i < hi; ++i) { out[i] = run; run += in[i]; }
    if (t == 0) out[n] = sums[1023];
}

__global__ void init_node(const int* __restrict__ degin, const int* __restrict__ degout,
                          const int* __restrict__ off_dst, const int* __restrict__ off_src,
                          int* __restrict__ cur_dst, int* __restrict__ cur_src,
                          float* __restrict__ dis, float* __restrict__ cntf) {
    int i = blockIdx.x * blockDim.x + threadIdx.x;
    if (i < NN) {
        dis[i] = rsqrtf((float)(degin[i] + 1));   // +1 self loop; always >0
        int od = degout[i];
        cntf[i] = (float)(od > 0 ? od : 1);
        cur_dst[i] = off_dst[i];
        cur_src[i] = off_src[i];
    }
}

__global__ void fill_csr(const int* __restrict__ src, const int* __restrict__ dst,
                         int* __restrict__ cur_dst, int* __restrict__ cur_src,
                         int* __restrict__ srcs_by_dst, int* __restrict__ dsts_by_src) {
    int e = blockIdx.x * blockDim.x + threadIdx.x;
    if (e < NE) {
        int s = src[e], d = dst[e];
        int p = atomicAdd(&cur_dst[d], 1);
        srcs_by_dst[p] = s;
        int q = atomicAdd(&cur_src[s], 1);
        dsts_by_src[q] = d;
    }
}

// ---------------- helpers ----------------

__device__ __forceinline__ float4 bfly_sum(float4 v) {
    v.x += __shfl_xor(v.x, 16); v.y += __shfl_xor(v.y, 16);
    v.z += __shfl_xor(v.z, 16); v.w += __shfl_xor(v.w, 16);
    v.x += __shfl_xor(v.x, 32); v.y += __shfl_xor(v.y, 32);
    v.z += __shfl_xor(v.z, 32); v.w += __shfl_xor(v.w, 32);
    return v;
}

// ---------------- GEMM: [n,K] @ [K,64], 64 rows per block ----------------
template<int K, bool RELU>
__global__ __launch_bounds__(256) void gemm64b(const float* __restrict__ X,
                                               const float* __restrict__ W,
                                               const float* __restrict__ bias,
                                               float* __restrict__ out, int n) {
    __shared__ float Ws[64 * 64];
    __shared__ float Xs[64][68];
    int tid = threadIdx.x;
    int row0 = blockIdx.x * 64;
    int r16 = tid >> 4;      // 0..15
    int cg = tid & 15;       // 0..15
    float4 acc[4];
#pragma unroll
    for (int t = 0; t < 4; ++t) acc[t] = make_float4(0.f, 0.f, 0.f, 0.f);

    for (int kc = 0; kc < K; kc += 64) {
        const float4* W4 = (const float4*)(W + (size_t)kc * 64);
        float4* Ws4 = (float4*)Ws;
#pragma unroll
        for (int t = 0; t < 4; ++t) Ws4[tid + t * 256] = W4[tid + t * 256];
#pragma unroll
        for (int t = 0; t < 4; ++t) {
            int r = r16 + t * 16;
            int grow = row0 + r;
            float4 xv = make_float4(0.f, 0.f, 0.f, 0.f);
            if (grow < n) xv = *(const float4*)(X + (size_t)grow * K + kc + cg * 4);
            Xs[r][cg * 4 + 0] = xv.x; Xs[r][cg * 4 + 1] = xv.y;
            Xs[r][cg * 4 + 2] = xv.z; Xs[r][cg * 4 + 3] = xv.w;
        }
        __syncthreads();
#pragma unroll
        for (int k = 0; k < 64; ++k) {
            float4 w4 = ((const float4*)Ws)[k * 16 + cg];
#pragma unroll
            for (int t = 0; t < 4; ++t) {
                float xv = Xs[r16 + t * 16][k];
                acc[t].x += xv * w4.x; acc[t].y += xv * w4.y;
                acc[t].z += xv * w4.z; acc[t].w += xv * w4.w;
            }
        }
        __syncthreads();
    }

    float4 b4 = ((const float4*)bias)[cg];
#pragma unroll
    for (int t = 0; t < 4; ++t) {
        int row = row0 + r16 + t * 16;
        if (row < n) {
            float4 o;
            o.x = acc[t].x + b4.x; o.y = acc[t].y + b4.y;
            o.z = acc[t].z + b4.z; o.w = acc[t].w + b4.w;
            if (RELU) {
                o.x = fmaxf(o.x, 0.f); o.y = fmaxf(o.y, 0.f);
                o.z = fmaxf(o.z, 0.f); o.w = fmaxf(o.w, 0.f);
            }
            ((float4*)(out + (size_t)row * 64))[cg] = o;
        }
    }
}

// ---------------- fused layer: Z-aggregation + dual GEMV ----------------
// Z[i] = dis_i * (sum_{s in in(i)} dis_s*X[s] + dis_i*X[i])
// B[i] = relu(Z[i] @ Wb + bb)   (conv candidate X_)
// C[i] = relu(Z[i] @ Wc + bc)   (gate xg)
__global__ __launch_bounds__(256) void fused_layer(
    const float* __restrict__ X,
    const float* __restrict__ Wb, const float* __restrict__ bb,
    const float* __restrict__ Wc, const float* __restrict__ bc,
    const int* __restrict__ off, const int* __restrict__ nbr,
    const float* __restrict__ dis,
    float* __restrict__ B, float* __restrict__ C)
{
    __shared__ float Ws[2][64 * 64];
    int tid = threadIdx.x;
    {
        const float4* wb4 = (const float4*)Wb;
        const float4* wc4 = (const float4*)Wc;
        float4* s0 = (float4*)Ws[0];
        float4* s1 = (float4*)Ws[1];
#pragma unroll
        for (int t = 0; t < 4; ++t) {
            s0[tid + t * 256] = wb4[tid + t * 256];
            s1[tid + t * 256] = wc4[tid + t * 256];
        }
    }
    __syncthreads();

    int lane = tid & 63;
    int q = lane >> 4;       // quarter 0..3
    int c = lane & 15;       // float4 group 0..15
    float4 bbv = ((const float4*)bb)[c];
    float4 bcv = ((const float4*)bc)[c];

    int wave = blockIdx.x * 4 + (tid >> 6);
    int node0 = wave * NPW;
    int nodeEnd = node0 + NPW; if (nodeEnd > NN) nodeEnd = NN;

    for (int node = node0; node < nodeEnd; ++node) {
        // gather: quarter q handles neighbors lo+q, lo+q+4, ...
        float4 z = make_float4(0.f, 0.f, 0.f, 0.f);
        int lo = off[node], hi = off[node + 1];
        for (int j = lo + q; j < hi; j += 4) {
            int s = nbr[j];
            float ds = dis[s];
            float4 xs = *(const float4*)(X + (size_t)s * 64 + c * 4);
            z.x += ds * xs.x; z.y += ds * xs.y;
            z.z += ds * xs.z; z.w += ds * xs.w;
        }
        z = bfly_sum(z);
        float di = dis[node];
        float4 xi = *(const float4*)(X + (size_t)node * 64 + c * 4);
        z.x = di * (z.x + di * xi.x);
        z.y = di * (z.y + di * xi.y);
        z.z = di * (z.z + di * xi.z);
        z.w = di * (z.w + di * xi.w);

        // dual GEMV: lane (q,c) covers k in [16q,16q+16), outputs 4c..4c+3
        float4 ab = make_float4(0.f, 0.f, 0.f, 0.f);
        float4 ac = make_float4(0.f, 0.f, 0.f, 0.f);
#pragma unroll
        for (int kk = 0; kk < 16; ++kk) {
            float zsrc = ((kk & 3) == 0) ? z.x : ((kk & 3) == 1) ? z.y
                       : ((kk & 3) == 2) ? z.z : z.w;
            float zk = __shfl(zsrc, q * 4 + (kk >> 2));
            int k = q * 16 + kk;
            float4 wb = *(const float4*)&Ws[0][k * 64 + c * 4];
            float4 wc = *(const float4*)&Ws[1][k * 64 + c * 4];
            ab.x += zk * wb.x; ab.y += zk * wb.y; ab.z += zk * wb.z; ab.w += zk * wb.w;
            ac.x += zk * wc.x; ac.y += zk * wc.y; ac.z += zk * wc.z; ac.w += zk * wc.w;
        }
        ab = bfly_sum(ab);
        ac = bfly_sum(ac);
        if (q == 0) {
            float4 o;
            o.x = fmaxf(ab.x + bbv.x, 0.f); o.y = fmaxf(ab.y + bbv.y, 0.f);
            o.z = fmaxf(ab.z + bbv.z, 0.f); o.w = fmaxf(ab.w + bbv.w, 0.f);
            *(float4*)(B + (size_t)node * 64 + c * 4) = o;
        } else if (q == 1) {
            float4 o;
            o.x = fmaxf(ac.x + bcv.x, 0.f); o.y = fmaxf(ac.y + bcv.y, 0.f);
            o.z = fmaxf(ac.z + bcv.z, 0.f); o.w = fmaxf(ac.w + bcv.w, 0.f);
            *(float4*)(C + (size_t)node * 64 + c * 4) = o;
        }
    }
}

// ---------------- gate + convex update ----------------
// tau = tanh( sum_{d in out(i)} (xg_i - xg_d)^2 / cnt_i )   per channel
// X = (1-tau)*X + tau*Xn
__global__ __launch_bounds__(256) void gate_update4(
    const float* __restrict__ XG, const float* __restrict__ Xn,
    float* __restrict__ X,
    const int* __restrict__ off, const int* __restrict__ nbr,
    const float* __restrict__ cntf)
{
    int tid = threadIdx.x;
    int lane = tid & 63;
    int q = lane >> 4;
    int c = lane & 15;
    int wave = blockIdx.x * 4 + (tid >> 6);
    int node0 = wave * NPW;
    int nodeEnd = node0 + NPW; if (nodeEnd > NN) nodeEnd = NN;

    for (int node = node0; node < nodeEnd; ++node) {
        float4 xg = *(const float4*)(XG + (size_t)node * 64 + c * 4);
        float4 acc = make_float4(0.f, 0.f, 0.f, 0.f);
        int lo = off[node], hi = off[node + 1];
        for (int j = lo + q; j < hi; j += 4) {
            int d = nbr[j];
            float4 xd = *(const float4*)(XG + (size_t)d * 64 + c * 4);
            float ex = xg.x - xd.x, ey = xg.y - xd.y;
            float ez = xg.z - xd.z, ew = xg.w - xd.w;
            acc.x += ex * ex; acc.y += ey * ey;
            acc.z += ez * ez; acc.w += ew * ew;
        }
        acc = bfly_sum(acc);
        if (q == 0) {
            float inv = 1.f / cntf[node];
            float4 tau;
            tau.x = tanhf(acc.x * inv); tau.y = tanhf(acc.y * inv);
            tau.z = tanhf(acc.z * inv); tau.w = tanhf(acc.w * inv);
            float4 xo = *(const float4*)(X + (size_t)node * 64 + c * 4);
            float4 xn = *(const float4*)(Xn + (size_t)node * 64 + c * 4);
            float4 o;
            o.x = xo.x + tau.x * (xn.x - xo.x);
            o.y = xo.y + tau.y * (xn.y - xo.y);
            o.z = xo.z + tau.z * (xn.z - xo.z);
            o.w = xo.w + tau.w * (xn.w - xo.w);
            *(float4*)(X + (size_t)node * 64 + c * 4) = o;
        }
    }
}

// ---------------- launch ----------------

extern "C" void kernel_launch(void* const* d_in, const int* in_sizes, int n_in,
                              void* d_out, int out_size, void* d_ws, size_t ws_size,
                              hipStream_t stream) {
    const float* x      = (const float*)d_in[0];
    const int*   ei     = (const int*)d_in[1];
    const float* enc_w  = (const float*)d_in[2];
    const float* enc_b  = (const float*)d_in[3];
    const float* conv_w = (const float*)d_in[4];
    const float* conv_b = (const float*)d_in[5];
    const float* gg_w   = (const float*)d_in[6];
    const float* gg_b   = (const float*)d_in[7];
    const float* dec_w  = (const float*)d_in[8];
    const float* dec_b  = (const float*)d_in[9];
    float* out = (float*)d_out;

    const int* src = ei;
    const int* dst = ei + NE;

    char* p = (char*)d_ws;
    auto alloc = [&](size_t bytes) -> void* {
        void* r = (void*)p;
        p += (bytes + 255) & ~(size_t)255;
        return r;
    };
    float* X    = (float*)alloc((size_t)NN * 64 * 4);
    float* B    = (float*)alloc((size_t)NN * 64 * 4);   // X_ candidate
    float* C    = (float*)alloc((size_t)NN * 64 * 4);   // xg
    float* dis  = (float*)alloc((size_t)NN * 4);
    float* cntf = (float*)alloc((size_t)NN * 4);
    int* degin   = (int*)alloc((size_t)NN * 4);
    int* degout  = (int*)alloc((size_t)NN * 4);
    int* off_dst = (int*)alloc((size_t)(NN + 1) * 4);
    int* off_src = (int*)alloc((size_t)(NN + 1) * 4);
    int* cur_dst = (int*)alloc((size_t)NN * 4);
    int* cur_src = (int*)alloc((size_t)NN * 4);
    int* sbd     = (int*)alloc((size_t)NE * 4);   // srcs grouped by dst
    int* dbs     = (int*)alloc((size_t)NE * 4);   // dsts grouped by src

    hipMemsetAsync(degin, 0, (size_t)NN * 4, stream);
    hipMemsetAsync(degout, 0, (size_t)NN * 4, stream);

    const int EB = (NE + 255) / 256;
    const int NB = (NN + 255) / 256;
    count_deg<<<EB, 256, 0, stream>>>(src, dst, degin, degout);
    scan_excl<<<1, 1024, 0, stream>>>(degin, off_dst, NN);
    scan_excl<<<1, 1024, 0, stream>>>(degout, off_src, NN);
    init_node<<<NB, 256, 0, stream>>>(degin, degout, off_dst, off_src,
                                      cur_dst, cur_src, dis, cntf);
    fill_csr<<<EB, 256, 0, stream>>>(src, dst, cur_dst, cur_src, sbd, dbs);

    const int GB = (NN + 63) / 64;                       // gemm blocks (64 rows each)
    const int WB = ((NN + NPW - 1) / NPW + 3) / 4;       // gather blocks (4 waves, NPW nodes/wave)

    // encoder
    gemm64b<IND, true><<<GB, 256, 0, stream>>>(x, enc_w, enc_b, X, NN);

    for (int l = 0; l < DEPTH; ++l) {
        fused_layer<<<WB, 256, 0, stream>>>(X, conv_w, conv_b, gg_w, gg_b,
                                            off_dst, sbd, dis, B, C);
        gate_update4<<<WB, 256, 0, stream>>>(C, B, X, off_src, dbs, cntf);
    }

    // decoder
    gemm64b<NH, true><<<GB, 256, 0, stream>>>(X, dec_w, dec_b, out, NN);
}